// Round 1
// baseline (584.495 us; speedup 1.0000x reference)
//
#include <hip/hip_runtime.h>

typedef short s16x8 __attribute__((ext_vector_type(8)));
typedef float f32x4 __attribute__((ext_vector_type(4)));
typedef unsigned short ushort;

// ---------------- problem constants ----------------
#define NTOK 1024
#define DHID 512

// head: W0 (20000) + cluster_weight (3) = 20003 rows, K=512
#define VH   20003
#define KH   512
#define NCH_H 32
#define TPC_H 40      // 32 chunks * 40 tiles * 16 = 20480 padded rows
#define VH_PAD 20480

// tail1: 20000 rows, K=128
#define V1   20000
#define K1   128
#define NCH_1 16
#define TPC_1 80      // 16*80*16 = 20480
#define V1_PAD 20480

// tail2: 160000 rows, K=32
#define V2   160000
#define K2   32
#define NCH_2 32
#define TPC_2 316     // 32*316*16 = 161792
#define V2_PAD 161792

// tail3: 67735 rows, K=8 padded to 32
#define V3   67735
#define K3   32
#define NCH_3 16
#define TPC_3 268     // 16*268*16 = 68608
#define V3_PAD 68608

// ---------------- ws layout (bytes) ----------------
#define OFF_HW   0UL
#define OFF_W1   (OFF_HW  + (unsigned long)VH_PAD*KH*2)
#define OFF_W2   (OFF_W1  + (unsigned long)V1_PAD*K1*2)
#define OFF_W3   (OFF_W2  + (unsigned long)V2_PAD*K2*2)
#define OFF_HID  (OFF_W3  + (unsigned long)V3_PAD*K3*2)
#define OFF_PT0  (OFF_HID + (unsigned long)NTOK*DHID*2)
#define OFF_PT1  (OFF_PT0 + (unsigned long)512*DHID*2)
#define OFF_PT2  (OFF_PT1 + (unsigned long)128*DHID*2)
#define OFF_PT3  (OFF_PT2 + (unsigned long)32*DHID*2)
#define OFF_H0   (OFF_PT3 + (unsigned long)32*DHID*2)
#define OFF_H1   (OFF_H0  + (unsigned long)NTOK*512*2)
#define OFF_H2   (OFF_H1  + (unsigned long)NTOK*128*2)
#define OFF_H3   (OFF_H2  + (unsigned long)NTOK*32*2)
#define OFF_HB   (OFF_H3  + (unsigned long)NTOK*32*2)
#define OFF_B1   (OFF_HB  + (unsigned long)VH_PAD*4)
#define OFF_B2   (OFF_B1  + (unsigned long)V1_PAD*4)
#define OFF_B3   (OFF_B2  + (unsigned long)V2_PAD*4)
#define OFF_SH   (OFF_B3  + (unsigned long)V3_PAD*4)
#define OFF_S1   (OFF_SH  + (unsigned long)NTOK*NCH_H*4)
#define OFF_S2   (OFF_S1  + (unsigned long)NTOK*NCH_1*4)
#define OFF_S3   (OFF_S2  + (unsigned long)NTOK*NCH_2*4)

// ---------------- helpers ----------------
__device__ __forceinline__ ushort f2bf(float f) {
    union { float f; unsigned u; } x; x.f = f;
    unsigned r = x.u + 0x7fffu + ((x.u >> 16) & 1u);
    return (ushort)(r >> 16);
}
__device__ __forceinline__ float bf2f(ushort h) {
    union { unsigned u; float f; } x; x.u = ((unsigned)h) << 16;
    return x.f;
}
__device__ __forceinline__ f32x4 mfma_bf16(s16x8 a, s16x8 b, f32x4 c) {
    return __builtin_amdgcn_mfma_f32_16x16x32_bf16(a, b, c, 0, 0, 0);
}

// ---------------- prep: fp32 -> bf16 conversions, padding, transposes ----------------
// section element counts
#define E_HW  ((long)VH_PAD*KH)      // 10485760
#define E_W1  ((long)V1_PAD*K1)      // 2621440
#define E_W2  ((long)V2_PAD*K2)      // 5177344
#define E_W3  ((long)V3_PAD*K3)      // 2195456
#define E_HID ((long)NTOK*DHID)      // 524288
#define E_PT0 ((long)512*DHID)
#define E_PT1 ((long)128*DHID)
#define E_PT2 ((long)32*DHID)
#define E_PT3 ((long)32*DHID)
#define E_HB  ((long)VH_PAD)
#define E_B1  ((long)V1_PAD)
#define E_B2  ((long)V2_PAD)
#define E_B3  ((long)V3_PAD)
#define E_TOTAL (E_HW+E_W1+E_W2+E_W3+E_HID+E_PT0+E_PT1+E_PT2+E_PT3+E_HB+E_B1+E_B2+E_B3)

__global__ __launch_bounds__(256) void prep_kernel(
    const float* __restrict__ hidden,
    const float* __restrict__ W0, const float* __restrict__ b0, const float* __restrict__ p0,
    const float* __restrict__ W1, const float* __restrict__ b1, const float* __restrict__ p1,
    const float* __restrict__ W2, const float* __restrict__ b2, const float* __restrict__ p2,
    const float* __restrict__ W3, const float* __restrict__ b3, const float* __restrict__ p3,
    const float* __restrict__ cw, const float* __restrict__ cb,
    ushort* __restrict__ hw, ushort* __restrict__ ow1, ushort* __restrict__ ow2, ushort* __restrict__ ow3,
    ushort* __restrict__ hid,
    ushort* __restrict__ pT0, ushort* __restrict__ pT1, ushort* __restrict__ pT2, ushort* __restrict__ pT3,
    float* __restrict__ hbp, float* __restrict__ ob1, float* __restrict__ ob2, float* __restrict__ ob3)
{
    long stride = (long)gridDim.x * blockDim.x;
    for (long i = (long)blockIdx.x * blockDim.x + threadIdx.x; i < E_TOTAL; i += stride) {
        long j = i;
        if (j < E_HW) {                       // head weights [20480][512]
            long v = j >> 9, k = j & 511;
            float val = (v < 20000) ? W0[v*512 + k]
                       : (v < 20003) ? cw[(v - 20000)*512 + k] : 0.f;
            hw[j] = f2bf(val);
        } else if ((j -= E_HW) < E_W1) {      // W1 [20480][128]
            long v = j >> 7, k = j & 127;
            ow1[j] = f2bf(v < V1 ? W1[v*128 + k] : 0.f);
        } else if ((j -= E_W1) < E_W2) {      // W2 [161792][32]
            long v = j >> 5, k = j & 31;
            ow2[j] = f2bf(v < V2 ? W2[v*32 + k] : 0.f);
        } else if ((j -= E_W2) < E_W3) {      // W3 [68608][32], src K=8
            long v = j >> 5, k = j & 31;
            ow3[j] = f2bf((v < V3 && k < 8) ? W3[v*8 + k] : 0.f);
        } else if ((j -= E_W3) < E_HID) {     // hidden [1024][512]
            hid[j] = f2bf(hidden[j]);
        } else if ((j -= E_HID) < E_PT0) {    // projT0 [512][512]
            long c = j >> 9, k = j & 511;
            pT0[j] = f2bf(p0[k*512 + c]);
        } else if ((j -= E_PT0) < E_PT1) {    // projT1 [128][512]
            long c = j >> 9, k = j & 511;
            pT1[j] = f2bf(p1[k*128 + c]);
        } else if ((j -= E_PT1) < E_PT2) {    // projT2 [32][512]
            long c = j >> 9, k = j & 511;
            pT2[j] = f2bf(p2[k*32 + c]);
        } else if ((j -= E_PT2) < E_PT3) {    // projT3 [32][512], src d=8
            long c = j >> 9, k = j & 511;
            pT3[j] = f2bf(c < 8 ? p3[k*8 + c] : 0.f);
        } else if ((j -= E_PT3) < E_HB) {     // head bias padded
            hbp[j] = (j < 20000) ? b0[j] : (j < 20003) ? cb[j - 20000] : 0.f;
        } else if ((j -= E_HB) < E_B1) {
            ob1[j] = (j < V1) ? b1[j] : 0.f;
        } else if ((j -= E_B1) < E_B2) {
            ob2[j] = (j < V2) ? b2[j] : 0.f;
        } else { j -= E_B2;
            ob3[j] = (j < V3) ? b3[j] : 0.f;
        }
    }
}

// ---------------- gemm_h: H_i = hidden @ proj_i  (MFMA 16x16x32) ----------------
// A = hidden bf16 [1024][512] row-major; B = projT [dpad][512] (row n holds proj[:,n])
__global__ __launch_bounds__(256) void gemm_h(
    const ushort* __restrict__ A, const ushort* __restrict__ Bt,
    ushort* __restrict__ Hout, int dpad)
{
    int wave = threadIdx.x >> 6, lane = threadIdx.x & 63;
    int quad = lane >> 4, colid = lane & 15;
    int m0 = blockIdx.x * 64 + wave * 16;
    int c0 = blockIdx.y * 16;
    f32x4 acc = {0.f, 0.f, 0.f, 0.f};
    const ushort* Ar = A + (long)(m0 + colid) * DHID + quad * 8;
    const ushort* Br = Bt + (long)(c0 + colid) * DHID + quad * 8;
    #pragma unroll 4
    for (int s = 0; s < DHID / 32; ++s) {
        s16x8 a = *(const s16x8*)(Ar + s * 32);
        s16x8 b = *(const s16x8*)(Br + s * 32);
        acc = mfma_bf16(a, b, acc);
    }
    #pragma unroll
    for (int r = 0; r < 4; ++r) {
        int m = m0 + quad * 4 + r;
        Hout[(long)m * dpad + c0 + colid] = f2bf(acc[r]);
    }
}

// ---------------- fused GEMM + exp-sum over vocab chunk ----------------
// A [1024][K] bf16, W [Vpad][K] bf16, bias [Vpad] f32.
// Writes part_s[token][chunk] = sum_{c in chunk, c < V} exp(A[m]·W[c] + bias[c])
__global__ __launch_bounds__(256) void fused_lse(
    const ushort* __restrict__ A, const ushort* __restrict__ W,
    const float* __restrict__ bias, float* __restrict__ part_s,
    int K, int V, int tpc, int n_chunks)
{
    int wave = threadIdx.x >> 6, lane = threadIdx.x & 63;
    int quad = lane >> 4, colid = lane & 15;
    int m0 = blockIdx.x * 64 + wave * 16;
    int chunk = blockIdx.y;
    long t0 = (long)chunk * tpc;
    int ksteps = K >> 5;

    const ushort* Arow = A + (long)(m0 + colid) * K + quad * 8;
    float s_acc[4] = {0.f, 0.f, 0.f, 0.f};

    for (int vt = 0; vt < tpc; vt += 4) {
        long vbase = (t0 + vt) * 16;
        if (vbase >= V) break;
        f32x4 acc[4];
        #pragma unroll
        for (int u = 0; u < 4; ++u) acc[u] = (f32x4){0.f, 0.f, 0.f, 0.f};
        const ushort* Wrow = W + (vbase + colid) * (long)K + quad * 8;
        for (int s = 0; s < ksteps; ++s) {
            s16x8 a  = *(const s16x8*)(Arow + s * 32);
            s16x8 b0 = *(const s16x8*)(Wrow + s * 32);
            s16x8 b1 = *(const s16x8*)(Wrow + 16L * K + s * 32);
            s16x8 b2 = *(const s16x8*)(Wrow + 32L * K + s * 32);
            s16x8 b3 = *(const s16x8*)(Wrow + 48L * K + s * 32);
            acc[0] = mfma_bf16(a, b0, acc[0]);
            acc[1] = mfma_bf16(a, b1, acc[1]);
            acc[2] = mfma_bf16(a, b2, acc[2]);
            acc[3] = mfma_bf16(a, b3, acc[3]);
        }
        #pragma unroll
        for (int u = 0; u < 4; ++u) {
            long c = vbase + u * 16 + colid;
            bool valid = (c < V);
            float bval = valid ? bias[c] : 0.f;
            #pragma unroll
            for (int r = 0; r < 4; ++r) {
                float l = acc[u][r] + bval;
                s_acc[r] += valid ? __expf(l) : 0.f;
            }
        }
    }
    // butterfly sum over the 16 lanes of this quad-group (cols), then write
    #pragma unroll
    for (int r = 0; r < 4; ++r) {
        float v = s_acc[r];
        v += __shfl_xor(v, 1);
        v += __shfl_xor(v, 2);
        v += __shfl_xor(v, 4);
        v += __shfl_xor(v, 8);
        s_acc[r] = v;
    }
    if (colid == 0) {
        #pragma unroll
        for (int r = 0; r < 4; ++r) {
            int m = m0 + quad * 4 + r;
            part_s[(long)m * n_chunks + chunk] = s_acc[r];
        }
    }
}

// ---------------- finalize: one wave per token ----------------
__global__ __launch_bounds__(256) void finalize_kernel(
    const int* __restrict__ target,
    const ushort* __restrict__ H0, const ushort* __restrict__ hw,
    const float* __restrict__ hbp, const float* __restrict__ sH,
    const ushort* __restrict__ H1, const ushort* __restrict__ w1,
    const float* __restrict__ b1p, const float* __restrict__ s1,
    const ushort* __restrict__ H2, const ushort* __restrict__ w2,
    const float* __restrict__ b2p, const float* __restrict__ s2,
    const ushort* __restrict__ H3, const ushort* __restrict__ w3,
    const float* __restrict__ b3p, const float* __restrict__ s3,
    float* __restrict__ out)
{
    int wave = threadIdx.x >> 6, lane = threadIdx.x & 63;
    int m = blockIdx.x * 4 + wave;
    int t = target[m];
    int cid = (t >= 20000) + (t >= 40000) + (t >= 200000);

    // head log-sum-exp from partials
    float s = (lane < NCH_H) ? sH[(long)m * NCH_H + lane] : 0.f;
    s += __shfl_xor(s, 1);  s += __shfl_xor(s, 2);  s += __shfl_xor(s, 4);
    s += __shfl_xor(s, 8);  s += __shfl_xor(s, 16); s += __shfl_xor(s, 32);
    float lse_h = __logf(s);

    // head target-column logit (column = target for shortlist, 20003-cid for tails)
    int hc = (cid == 0) ? t : (20003 - cid);
    float d = 0.f;
    {
        const ushort* hr = H0 + (long)m * 512 + lane * 8;
        const ushort* wr = hw + (long)hc * 512 + lane * 8;
        #pragma unroll
        for (int j = 0; j < 8; ++j) d += bf2f(hr[j]) * bf2f(wr[j]);
        d += __shfl_xor(d, 1);  d += __shfl_xor(d, 2);  d += __shfl_xor(d, 4);
        d += __shfl_xor(d, 8);  d += __shfl_xor(d, 16); d += __shfl_xor(d, 32);
    }
    float nll = lse_h - (d + hbp[hc]);

    if (cid > 0) {
        const ushort *Hi, *Wi; const float *bi, *si; int K, nc, l;
        if (cid == 1)      { Hi = H1; Wi = w1; bi = b1p; si = s1; K = 128; nc = NCH_1; l = 20000; }
        else if (cid == 2) { Hi = H2; Wi = w2; bi = b2p; si = s2; K = 32;  nc = NCH_2; l = 40000; }
        else               { Hi = H3; Wi = w3; bi = b3p; si = s3; K = 32;  nc = NCH_3; l = 200000; }
        int rel = t - l;
        float ts = (lane < nc) ? si[(long)m * nc + lane] : 0.f;
        ts += __shfl_xor(ts, 1);  ts += __shfl_xor(ts, 2);  ts += __shfl_xor(ts, 4);
        ts += __shfl_xor(ts, 8);  ts += __shfl_xor(ts, 16); ts += __shfl_xor(ts, 32);
        float lse_t = __logf(ts);

        float dt = 0.f;
        if (lane * 8 < K) {
            const ushort* hr = Hi + (long)m * K + lane * 8;
            const ushort* wr = Wi + (long)rel * K + lane * 8;
            #pragma unroll
            for (int j = 0; j < 8; ++j) dt += bf2f(hr[j]) * bf2f(wr[j]);
        }
        dt += __shfl_xor(dt, 1);  dt += __shfl_xor(dt, 2);  dt += __shfl_xor(dt, 4);
        dt += __shfl_xor(dt, 8);  dt += __shfl_xor(dt, 16); dt += __shfl_xor(dt, 32);
        nll += lse_t - (dt + bi[rel]);
    }
    if (lane == 0) out[m] = nll;
}

// ---------------- host ----------------
extern "C" void kernel_launch(void* const* d_in, const int* in_sizes, int n_in,
                              void* d_out, int out_size, void* d_ws, size_t ws_size,
                              hipStream_t stream) {
    const float* hidden = (const float*)d_in[0];
    const int*   target = (const int*)d_in[1];
    const float* W0 = (const float*)d_in[2];
    const float* b0 = (const float*)d_in[3];
    const float* p0 = (const float*)d_in[4];
    const float* W1 = (const float*)d_in[5];
    const float* b1 = (const float*)d_in[6];
    const float* p1 = (const float*)d_in[7];
    const float* W2 = (const float*)d_in[8];
    const float* b2 = (const float*)d_in[9];
    const float* p2 = (const float*)d_in[10];
    const float* W3 = (const float*)d_in[11];
    const float* b3 = (const float*)d_in[12];
    const float* p3 = (const float*)d_in[13];
    const float* cw = (const float*)d_in[14];
    const float* cb = (const float*)d_in[15];

    char* ws = (char*)d_ws;
    ushort* hw  = (ushort*)(ws + OFF_HW);
    ushort* ow1 = (ushort*)(ws + OFF_W1);
    ushort* ow2 = (ushort*)(ws + OFF_W2);
    ushort* ow3 = (ushort*)(ws + OFF_W3);
    ushort* hid = (ushort*)(ws + OFF_HID);
    ushort* pT0 = (ushort*)(ws + OFF_PT0);
    ushort* pT1 = (ushort*)(ws + OFF_PT1);
    ushort* pT2 = (ushort*)(ws + OFF_PT2);
    ushort* pT3 = (ushort*)(ws + OFF_PT3);
    ushort* H0  = (ushort*)(ws + OFF_H0);
    ushort* H1  = (ushort*)(ws + OFF_H1);
    ushort* H2  = (ushort*)(ws + OFF_H2);
    ushort* H3  = (ushort*)(ws + OFF_H3);
    float* hbp = (float*)(ws + OFF_HB);
    float* b1p = (float*)(ws + OFF_B1);
    float* b2p = (float*)(ws + OFF_B2);
    float* b3p = (float*)(ws + OFF_B3);
    float* sH  = (float*)(ws + OFF_SH);
    float* s1  = (float*)(ws + OFF_S1);
    float* s2  = (float*)(ws + OFF_S2);
    float* s3  = (float*)(ws + OFF_S3);

    prep_kernel<<<4096, 256, 0, stream>>>(hidden, W0, b0, p0, W1, b1, p1, W2, b2, p2,
                                          W3, b3, p3, cw, cb,
                                          hw, ow1, ow2, ow3, hid, pT0, pT1, pT2, pT3,
                                          hbp, b1p, b2p, b3p);

    gemm_h<<<dim3(NTOK / 64, 512 / 16), 256, 0, stream>>>(hid, pT0, H0, 512);
    gemm_h<<<dim3(NTOK / 64, 128 / 16), 256, 0, stream>>>(hid, pT1, H1, 128);
    gemm_h<<<dim3(NTOK / 64, 32 / 16),  256, 0, stream>>>(hid, pT2, H2, 32);
    gemm_h<<<dim3(NTOK / 64, 32 / 16),  256, 0, stream>>>(hid, pT3, H3, 32);

    fused_lse<<<dim3(NTOK / 64, NCH_H), 256, 0, stream>>>(H0, hw,  hbp, sH, KH, VH, TPC_H, NCH_H);
    fused_lse<<<dim3(NTOK / 64, NCH_1), 256, 0, stream>>>(H1, ow1, b1p, s1, K1, V1, TPC_1, NCH_1);
    fused_lse<<<dim3(NTOK / 64, NCH_2), 256, 0, stream>>>(H2, ow2, b2p, s2, K2, V2, TPC_2, NCH_2);
    fused_lse<<<dim3(NTOK / 64, NCH_3), 256, 0, stream>>>(H3, ow3, b3p, s3, K3, V3, TPC_3, NCH_3);

    finalize_kernel<<<NTOK / 4, 256, 0, stream>>>(target,
        H0, hw, hbp, sH, H1, ow1, b1p, s1, H2, ow2, b2p, s2, H3, ow3, b3p, s3,
        (float*)d_out);
}

// Round 2
// 466.259 us; speedup vs baseline: 1.2536x; 1.2536x over previous
//
#include <hip/hip_runtime.h>

typedef short s16x8 __attribute__((ext_vector_type(8)));
typedef float f32x4 __attribute__((ext_vector_type(4)));
typedef unsigned short ushort;

// ---------------- problem constants ----------------
#define NTOK 1024
#define DHID 512

// head: W0 (20000) + cluster_weight (3) = 20003 rows, K=512
#define VH   20003
#define KH   512
#define NCH_H 40
#define TPC_H 32      // 40 chunks * 32 tiles * 16 = 20480 padded rows
#define VH_PAD 20480

// tail1: 20000 rows, K=128
#define V1   20000
#define K1   128
#define NCH_1 40
#define TPC_1 32      // 40*32*16 = 20480
#define V1_PAD 20480

// tail2: 160000 rows, K=32
#define V2   160000
#define K2   32
#define NCH_2 80
#define TPC_2 128     // 80*128*16 = 163840
#define V2_PAD 163840

// tail3: 67735 rows, K=8 padded to 32
#define V3   67735
#define K3   32
#define NCH_3 68
#define TPC_3 64      // 68*64*16 = 69632
#define V3_PAD 69632

// ---------------- ws layout (bytes) ----------------
#define OFF_HW   0UL
#define OFF_W1   (OFF_HW  + (unsigned long)VH_PAD*KH*2)
#define OFF_W2   (OFF_W1  + (unsigned long)V1_PAD*K1*2)
#define OFF_W3   (OFF_W2  + (unsigned long)V2_PAD*K2*2)
#define OFF_HID  (OFF_W3  + (unsigned long)V3_PAD*K3*2)
#define OFF_PT0  (OFF_HID + (unsigned long)NTOK*DHID*2)
#define OFF_PT1  (OFF_PT0 + (unsigned long)512*DHID*2)
#define OFF_PT2  (OFF_PT1 + (unsigned long)128*DHID*2)
#define OFF_PT3  (OFF_PT2 + (unsigned long)32*DHID*2)
#define OFF_H0   (OFF_PT3 + (unsigned long)32*DHID*2)
#define OFF_H1   (OFF_H0  + (unsigned long)NTOK*512*2)
#define OFF_H2   (OFF_H1  + (unsigned long)NTOK*128*2)
#define OFF_H3   (OFF_H2  + (unsigned long)NTOK*32*2)
#define OFF_HB   (OFF_H3  + (unsigned long)NTOK*32*2)
#define OFF_B1   (OFF_HB  + (unsigned long)VH_PAD*4)
#define OFF_B2   (OFF_B1  + (unsigned long)V1_PAD*4)
#define OFF_B3   (OFF_B2  + (unsigned long)V2_PAD*4)
#define OFF_SH   (OFF_B3  + (unsigned long)V3_PAD*4)
#define OFF_S1   (OFF_SH  + (unsigned long)NTOK*NCH_H*4)
#define OFF_S2   (OFF_S1  + (unsigned long)NTOK*NCH_1*4)
#define OFF_S3   (OFF_S2  + (unsigned long)NTOK*NCH_2*4)

#define PAD_BIAS (-1e30f)

// ---------------- helpers ----------------
__device__ __forceinline__ ushort f2bf(float f) {
    union { float f; unsigned u; } x; x.f = f;
    unsigned r = x.u + 0x7fffu + ((x.u >> 16) & 1u);
    return (ushort)(r >> 16);
}
__device__ __forceinline__ float bf2f(ushort h) {
    union { unsigned u; float f; } x; x.u = ((unsigned)h) << 16;
    return x.f;
}
__device__ __forceinline__ f32x4 mfma_bf16(s16x8 a, s16x8 b, f32x4 c) {
    return __builtin_amdgcn_mfma_f32_16x16x32_bf16(a, b, c, 0, 0, 0);
}

// ---------------- prep (vectorized big sections) ----------------
// big sections: HW, W1, W2, W3, HID  (all element counts divisible by 4,
// and every 4-aligned group of 4 stays within one source row / one branch)
#define E_HW  ((long)VH_PAD*KH)      // 10485760
#define E_W1  ((long)V1_PAD*K1)      // 2621440
#define E_W2  ((long)V2_PAD*K2)      // 5242880
#define E_W3  ((long)V3_PAD*K3)      // 2228224
#define E_HID ((long)NTOK*DHID)      // 524288
#define E_BIG (E_HW+E_W1+E_W2+E_W3+E_HID)   // 21102592

struct us4 { ushort x, y, z, w; };

__global__ __launch_bounds__(256) void prep_big(
    const float* __restrict__ hidden,
    const float* __restrict__ W0, const float* __restrict__ W1,
    const float* __restrict__ W2, const float* __restrict__ W3,
    const float* __restrict__ cw,
    ushort* __restrict__ hw, ushort* __restrict__ ow1,
    ushort* __restrict__ ow2, ushort* __restrict__ ow3,
    ushort* __restrict__ hid)
{
    long stride = (long)gridDim.x * blockDim.x;
    for (long g = (long)blockIdx.x * blockDim.x + threadIdx.x; g * 4 < E_BIG; g += stride) {
        long j = g * 4;
        float4 v = {0.f, 0.f, 0.f, 0.f};
        ushort* dst;
        long jj = j;
        if (jj < E_HW) {                         // head weights [20480][512]
            long row = jj >> 9, k = jj & 511;
            if (row < 20000)       v = *(const float4*)(W0 + jj);
            else if (row < 20003)  v = *(const float4*)(cw + (row - 20000) * 512 + k);
            dst = hw + jj;
        } else if ((jj -= E_HW) < E_W1) {        // W1 [20480][128]
            long row = jj >> 7;
            if (row < V1) v = *(const float4*)(W1 + jj);
            dst = ow1 + jj;
        } else if ((jj -= E_W1) < E_W2) {        // W2 [163840][32]
            long row = jj >> 5;
            if (row < V2) v = *(const float4*)(W2 + jj);
            dst = ow2 + jj;
        } else if ((jj -= E_W2) < E_W3) {        // W3 [69632][32], src K=8
            long row = jj >> 5, k = jj & 31;
            if (row < V3 && k < 8) v = *(const float4*)(W3 + row * 8 + k);
            dst = ow3 + jj;
        } else {                                 // hidden [1024][512]
            jj -= E_W2;  // now index into HID section? (jj was already -E_W2 path) 
            // NOTE: careful sequencing below
            dst = nullptr;
        }
        if (dst == nullptr) {                    // HID section
            long jh = j - (E_HW + E_W1 + E_W2 + E_W3);
            v = *(const float4*)(hidden + jh);
            dst = hid + jh;
        }
        us4 o; o.x = f2bf(v.x); o.y = f2bf(v.y); o.z = f2bf(v.z); o.w = f2bf(v.w);
        *(us4*)dst = o;
    }
}

// small sections: projT transposes + padded biases (scalar)
#define E_PT0 ((long)512*DHID)
#define E_PT1 ((long)128*DHID)
#define E_PT2 ((long)32*DHID)
#define E_PT3 ((long)32*DHID)
#define E_HB  ((long)VH_PAD)
#define E_B1  ((long)V1_PAD)
#define E_B2  ((long)V2_PAD)
#define E_B3  ((long)V3_PAD)
#define E_SMALL (E_PT0+E_PT1+E_PT2+E_PT3+E_HB+E_B1+E_B2+E_B3)

__global__ __launch_bounds__(256) void prep_small(
    const float* __restrict__ p0, const float* __restrict__ p1,
    const float* __restrict__ p2, const float* __restrict__ p3,
    const float* __restrict__ b0, const float* __restrict__ b1,
    const float* __restrict__ b2, const float* __restrict__ b3,
    const float* __restrict__ cb,
    ushort* __restrict__ pT0, ushort* __restrict__ pT1,
    ushort* __restrict__ pT2, ushort* __restrict__ pT3,
    float* __restrict__ hbp, float* __restrict__ ob1,
    float* __restrict__ ob2, float* __restrict__ ob3)
{
    long stride = (long)gridDim.x * blockDim.x;
    for (long i = (long)blockIdx.x * blockDim.x + threadIdx.x; i < E_SMALL; i += stride) {
        long j = i;
        if (j < E_PT0) {                      // projT0 [512][512]
            long c = j >> 9, k = j & 511;
            pT0[j] = f2bf(p0[k * 512 + c]);
        } else if ((j -= E_PT0) < E_PT1) {    // projT1 [128][512]
            long c = j >> 9, k = j & 511;
            pT1[j] = f2bf(p1[k * 128 + c]);
        } else if ((j -= E_PT1) < E_PT2) {    // projT2 [32][512]
            long c = j >> 9, k = j & 511;
            pT2[j] = f2bf(p2[k * 32 + c]);
        } else if ((j -= E_PT2) < E_PT3) {    // projT3 [32][512], src d=8
            long c = j >> 9, k = j & 511;
            pT3[j] = f2bf(c < 8 ? p3[k * 8 + c] : 0.f);
        } else if ((j -= E_PT3) < E_HB) {
            hbp[j] = (j < 20000) ? b0[j] : (j < VH) ? cb[j - 20000] : PAD_BIAS;
        } else if ((j -= E_HB) < E_B1) {
            ob1[j] = (j < V1) ? b1[j] : PAD_BIAS;
        } else if ((j -= E_B1) < E_B2) {
            ob2[j] = (j < V2) ? b2[j] : PAD_BIAS;
        } else { j -= E_B2;
            ob3[j] = (j < V3) ? b3[j] : PAD_BIAS;
        }
    }
}

// ---------------- gemm_h: H_i = hidden @ proj_i  (MFMA 16x16x32) ----------------
__global__ __launch_bounds__(256) void gemm_h(
    const ushort* __restrict__ A, const ushort* __restrict__ Bt,
    ushort* __restrict__ Hout, int dpad)
{
    int wave = threadIdx.x >> 6, lane = threadIdx.x & 63;
    int quad = lane >> 4, colid = lane & 15;
    int m0 = blockIdx.x * 64 + wave * 16;
    int c0 = blockIdx.y * 16;
    f32x4 acc = {0.f, 0.f, 0.f, 0.f};
    const ushort* Ar = A + (long)(m0 + colid) * DHID + quad * 8;
    const ushort* Br = Bt + (long)(c0 + colid) * DHID + quad * 8;
    #pragma unroll 4
    for (int s = 0; s < DHID / 32; ++s) {
        s16x8 a = *(const s16x8*)(Ar + s * 32);
        s16x8 b = *(const s16x8*)(Br + s * 32);
        acc = mfma_bf16(a, b, acc);
    }
    #pragma unroll
    for (int r = 0; r < 4; ++r) {
        int m = m0 + quad * 4 + r;
        Hout[(long)m * dpad + c0 + colid] = f2bf(acc[r]);
    }
}

// ---------------- fused GEMM + exp-sum over vocab chunk ----------------
// A [1024][K] bf16, W [Vpad][K] bf16 (pad rows zero), bias [Vpad] f32
// (pad entries = -1e30 so exp -> 0; no per-element guard needed).
// Each wave owns 16 tokens; streams U=8 vocab rows-of-16 per group.
template<int K>
__global__ __launch_bounds__(256, 2) void fused_lse_t(
    const ushort* __restrict__ A, const ushort* __restrict__ W,
    const float* __restrict__ bias, float* __restrict__ part_s,
    int tpc, int n_chunks)
{
    constexpr int U = 8;
    int wave = threadIdx.x >> 6, lane = threadIdx.x & 63;
    int quad = lane >> 4, colid = lane & 15;
    int m0 = blockIdx.x * 64 + wave * 16;
    long t0 = (long)blockIdx.y * tpc;

    const ushort* Arow = A + (long)(m0 + colid) * K + quad * 8;
    float s_acc[4] = {0.f, 0.f, 0.f, 0.f};

    for (int vt = 0; vt < tpc; vt += U) {
        long vbase = (t0 + vt) * 16;
        const ushort* Wrow = W + (vbase + colid) * (long)K + quad * 8;
        f32x4 acc[U];
        #pragma unroll
        for (int u = 0; u < U; ++u) acc[u] = (f32x4){0.f, 0.f, 0.f, 0.f};
        #pragma unroll
        for (int ks = 0; ks < K / 32; ++ks) {
            s16x8 a = *(const s16x8*)(Arow + ks * 32);
            #pragma unroll
            for (int u = 0; u < U; ++u) {
                s16x8 b = *(const s16x8*)(Wrow + (long)u * 16 * K + ks * 32);
                acc[u] = mfma_bf16(a, b, acc[u]);
            }
        }
        #pragma unroll
        for (int u = 0; u < U; ++u) {
            float bval = bias[vbase + u * 16 + colid];
            #pragma unroll
            for (int r = 0; r < 4; ++r)
                s_acc[r] += __expf(acc[u][r] + bval);
        }
    }
    #pragma unroll
    for (int r = 0; r < 4; ++r) {
        float v = s_acc[r];
        v += __shfl_xor(v, 1);
        v += __shfl_xor(v, 2);
        v += __shfl_xor(v, 4);
        v += __shfl_xor(v, 8);
        s_acc[r] = v;
    }
    if (colid == 0) {
        #pragma unroll
        for (int r = 0; r < 4; ++r) {
            int m = m0 + quad * 4 + r;
            part_s[(long)m * n_chunks + blockIdx.y] = s_acc[r];
        }
    }
}

// ---------------- finalize: one wave per token ----------------
__global__ __launch_bounds__(256) void finalize_kernel(
    const int* __restrict__ target,
    const ushort* __restrict__ H0, const ushort* __restrict__ hw,
    const float* __restrict__ hbp, const float* __restrict__ sH,
    const ushort* __restrict__ H1, const ushort* __restrict__ w1,
    const float* __restrict__ b1p, const float* __restrict__ s1,
    const ushort* __restrict__ H2, const ushort* __restrict__ w2,
    const float* __restrict__ b2p, const float* __restrict__ s2,
    const ushort* __restrict__ H3, const ushort* __restrict__ w3,
    const float* __restrict__ b3p, const float* __restrict__ s3,
    float* __restrict__ out)
{
    int wave = threadIdx.x >> 6, lane = threadIdx.x & 63;
    int m = blockIdx.x * 4 + wave;
    int t = target[m];
    int cid = (t >= 20000) + (t >= 40000) + (t >= 200000);

    // head log-sum-exp from partials
    float s = 0.f;
    for (int i = lane; i < NCH_H; i += 64) s += sH[(long)m * NCH_H + i];
    s += __shfl_xor(s, 1);  s += __shfl_xor(s, 2);  s += __shfl_xor(s, 4);
    s += __shfl_xor(s, 8);  s += __shfl_xor(s, 16); s += __shfl_xor(s, 32);
    float lse_h = __logf(s);

    // head target-column logit
    int hc = (cid == 0) ? t : (20003 - cid);
    float d = 0.f;
    {
        const ushort* hr = H0 + (long)m * 512 + lane * 8;
        const ushort* wr = hw + (long)hc * 512 + lane * 8;
        #pragma unroll
        for (int j = 0; j < 8; ++j) d += bf2f(hr[j]) * bf2f(wr[j]);
        d += __shfl_xor(d, 1);  d += __shfl_xor(d, 2);  d += __shfl_xor(d, 4);
        d += __shfl_xor(d, 8);  d += __shfl_xor(d, 16); d += __shfl_xor(d, 32);
    }
    float nll = lse_h - (d + hbp[hc]);

    if (cid > 0) {
        const ushort *Hi, *Wi; const float *bi, *si; int K, nc, l;
        if (cid == 1)      { Hi = H1; Wi = w1; bi = b1p; si = s1; K = 128; nc = NCH_1; l = 20000; }
        else if (cid == 2) { Hi = H2; Wi = w2; bi = b2p; si = s2; K = 32;  nc = NCH_2; l = 40000; }
        else               { Hi = H3; Wi = w3; bi = b3p; si = s3; K = 32;  nc = NCH_3; l = 200000; }
        int rel = t - l;
        float ts = 0.f;
        for (int i = lane; i < nc; i += 64) ts += si[(long)m * nc + i];
        ts += __shfl_xor(ts, 1);  ts += __shfl_xor(ts, 2);  ts += __shfl_xor(ts, 4);
        ts += __shfl_xor(ts, 8);  ts += __shfl_xor(ts, 16); ts += __shfl_xor(ts, 32);
        float lse_t = __logf(ts);

        float dt = 0.f;
        if (lane * 8 < K) {
            const ushort* hr = Hi + (long)m * K + lane * 8;
            const ushort* wr = Wi + (long)rel * K + lane * 8;
            #pragma unroll
            for (int j = 0; j < 8; ++j) dt += bf2f(hr[j]) * bf2f(wr[j]);
        }
        dt += __shfl_xor(dt, 1);  dt += __shfl_xor(dt, 2);  dt += __shfl_xor(dt, 4);
        dt += __shfl_xor(dt, 8);  dt += __shfl_xor(dt, 16); dt += __shfl_xor(dt, 32);
        nll += lse_t - (dt + bi[rel]);
    }
    if (lane == 0) out[m] = nll;
}

// ---------------- host ----------------
extern "C" void kernel_launch(void* const* d_in, const int* in_sizes, int n_in,
                              void* d_out, int out_size, void* d_ws, size_t ws_size,
                              hipStream_t stream) {
    const float* hidden = (const float*)d_in[0];
    const int*   target = (const int*)d_in[1];
    const float* W0 = (const float*)d_in[2];
    const float* b0 = (const float*)d_in[3];
    const float* p0 = (const float*)d_in[4];
    const float* W1 = (const float*)d_in[5];
    const float* b1 = (const float*)d_in[6];
    const float* p1 = (const float*)d_in[7];
    const float* W2 = (const float*)d_in[8];
    const float* b2 = (const float*)d_in[9];
    const float* p2 = (const float*)d_in[10];
    const float* W3 = (const float*)d_in[11];
    const float* b3 = (const float*)d_in[12];
    const float* p3 = (const float*)d_in[13];
    const float* cw = (const float*)d_in[14];
    const float* cb = (const float*)d_in[15];

    char* ws = (char*)d_ws;
    ushort* hw  = (ushort*)(ws + OFF_HW);
    ushort* ow1 = (ushort*)(ws + OFF_W1);
    ushort* ow2 = (ushort*)(ws + OFF_W2);
    ushort* ow3 = (ushort*)(ws + OFF_W3);
    ushort* hid = (ushort*)(ws + OFF_HID);
    ushort* pT0 = (ushort*)(ws + OFF_PT0);
    ushort* pT1 = (ushort*)(ws + OFF_PT1);
    ushort* pT2 = (ushort*)(ws + OFF_PT2);
    ushort* pT3 = (ushort*)(ws + OFF_PT3);
    ushort* H0  = (ushort*)(ws + OFF_H0);
    ushort* H1  = (ushort*)(ws + OFF_H1);
    ushort* H2  = (ushort*)(ws + OFF_H2);
    ushort* H3  = (ushort*)(ws + OFF_H3);
    float* hbp = (float*)(ws + OFF_HB);
    float* b1p = (float*)(ws + OFF_B1);
    float* b2p = (float*)(ws + OFF_B2);
    float* b3p = (float*)(ws + OFF_B3);
    float* sH  = (float*)(ws + OFF_SH);
    float* s1  = (float*)(ws + OFF_S1);
    float* s2  = (float*)(ws + OFF_S2);
    float* s3  = (float*)(ws + OFF_S3);

    prep_big<<<2048, 256, 0, stream>>>(hidden, W0, W1, W2, W3, cw,
                                       hw, ow1, ow2, ow3, hid);
    prep_small<<<1024, 256, 0, stream>>>(p0, p1, p2, p3, b0, b1, b2, b3, cb,
                                         pT0, pT1, pT2, pT3, hbp, b1p, b2p, b3p);

    gemm_h<<<dim3(NTOK / 64, 512 / 16), 256, 0, stream>>>(hid, pT0, H0, 512);
    gemm_h<<<dim3(NTOK / 64, 128 / 16), 256, 0, stream>>>(hid, pT1, H1, 128);
    gemm_h<<<dim3(NTOK / 64, 32 / 16),  256, 0, stream>>>(hid, pT2, H2, 32);
    gemm_h<<<dim3(NTOK / 64, 32 / 16),  256, 0, stream>>>(hid, pT3, H3, 32);

    fused_lse_t<KH><<<dim3(NTOK / 64, NCH_H), 256, 0, stream>>>(H0, hw,  hbp, sH, TPC_H, NCH_H);
    fused_lse_t<K1><<<dim3(NTOK / 64, NCH_1), 256, 0, stream>>>(H1, ow1, b1p, s1, TPC_1, NCH_1);
    fused_lse_t<K2><<<dim3(NTOK / 64, NCH_2), 256, 0, stream>>>(H2, ow2, b2p, s2, TPC_2, NCH_2);
    fused_lse_t<K3><<<dim3(NTOK / 64, NCH_3), 256, 0, stream>>>(H3, ow3, b3p, s3, TPC_3, NCH_3);

    finalize_kernel<<<NTOK / 4, 256, 0, stream>>>(target,
        H0, hw, hbp, sH, H1, ow1, b1p, s1, H2, ow2, b2p, s2, H3, ow3, b3p, s3,
        (float*)d_out);
}

// Round 3
// 277.806 us; speedup vs baseline: 2.1040x; 1.6784x over previous
//
#include <hip/hip_runtime.h>

typedef short s16x8 __attribute__((ext_vector_type(8)));
typedef unsigned short u16x8 __attribute__((ext_vector_type(8)));
typedef float f32x4 __attribute__((ext_vector_type(4)));
typedef unsigned short ushort;

// ---------------- problem constants ----------------
#define NTOK 1024
#define DHID 512

// head: W0 (20000) + cluster_weight (3) = 20003 rows, K=512
#define VH   20003
#define KH   512
#define NCH_H 80
#define TPC_H 16      // 80 chunks * 16 tiles * 16 = 20480 padded rows
#define VH_PAD 20480

// tail1: 20000 rows, K=128
#define V1   20000
#define K1   128
#define NCH_1 80
#define TPC_1 16      // 20480
#define V1_PAD 20480

// tail2: 160000 rows, K=32
#define V2   160000
#define K2   32
#define NCH_2 128
#define TPC_2 80      // 128*80*16 = 163840
#define V2_PAD 163840

// tail3: 67735 rows, K=8 padded to 32
#define V3   67735
#define K3   32
#define NCH_3 67
#define TPC_3 64      // 67*64*16 = 68608
#define V3_PAD 68608

#define PAD_BIAS (-1e30f)

// ---------------- ws layout (bytes) ----------------
// All MFMA operands live in "swizzled" layout: blocks of 512 elements
// (16 rows x 32 k), block index = tile*(K/32)+ks, element = lane*8+j where
// lane = quad*16 + r matches the mfma_16x16x32 A/B fragment mapping.
#define OFF_HW   0UL
#define OFF_W1   (OFF_HW  + (unsigned long)VH_PAD*KH*2)
#define OFF_W2   (OFF_W1  + (unsigned long)V1_PAD*K1*2)
#define OFF_W3   (OFF_W2  + (unsigned long)V2_PAD*K2*2)
#define OFF_HID  (OFF_W3  + (unsigned long)V3_PAD*K3*2)
#define OFF_PT0  (OFF_HID + (unsigned long)NTOK*DHID*2)
#define OFF_PT1  (OFF_PT0 + (unsigned long)512*DHID*2)
#define OFF_PT2  (OFF_PT1 + (unsigned long)128*DHID*2)
#define OFF_PT3  (OFF_PT2 + (unsigned long)32*DHID*2)
#define OFF_H0   (OFF_PT3 + (unsigned long)32*DHID*2)
#define OFF_H1   (OFF_H0  + (unsigned long)NTOK*512*2)
#define OFF_H2   (OFF_H1  + (unsigned long)NTOK*128*2)
#define OFF_H3   (OFF_H2  + (unsigned long)NTOK*32*2)
#define OFF_HB   (OFF_H3  + (unsigned long)NTOK*32*2)
#define OFF_B1   (OFF_HB  + (unsigned long)VH_PAD*4)
#define OFF_B2   (OFF_B1  + (unsigned long)V1_PAD*4)
#define OFF_B3   (OFF_B2  + (unsigned long)V2_PAD*4)
#define OFF_SH   (OFF_B3  + (unsigned long)V3_PAD*4)
#define OFF_S1   (OFF_SH  + (unsigned long)NTOK*NCH_H*4)
#define OFF_S2   (OFF_S1  + (unsigned long)NTOK*NCH_1*4)
#define OFF_S3   (OFF_S2  + (unsigned long)NTOK*NCH_2*4)

// ---------------- helpers ----------------
__device__ __forceinline__ ushort f2bf(float f) {
    union { float f; unsigned u; } x; x.f = f;
    unsigned r = x.u + 0x7fffu + ((x.u >> 16) & 1u);
    return (ushort)(r >> 16);
}
__device__ __forceinline__ float bf2f(ushort h) {
    union { unsigned u; float f; } x; x.u = ((unsigned)h) << 16;
    return x.f;
}
__device__ __forceinline__ f32x4 mfma_bf16(s16x8 a, s16x8 b, f32x4 c) {
    return __builtin_amdgcn_mfma_f32_16x16x32_bf16(a, b, c, 0, 0, 0);
}
__device__ __forceinline__ void ld8(const float* p, float* v) {
    float4 a = *(const float4*)p, b = *(const float4*)(p + 4);
    v[0]=a.x; v[1]=a.y; v[2]=a.z; v[3]=a.w; v[4]=b.x; v[5]=b.y; v[6]=b.z; v[7]=b.w;
}

// ---------------- prep: wave-per-512-element-block swizzle ----------------
#define WB_HW  20480L   // 1280 tiles * 16 ks
#define WB_W1  5120L    // 1280 * 4
#define WB_W2  10240L   // 10240 * 1
#define WB_W3  4288L    // 4288 * 1
#define WB_HID 1024L    // 64 * 16
#define WB_PT0 512L     // 32 * 16
#define WB_PT1 128L     // 8 * 16
#define WB_PT2 32L      // 2 * 16
#define WB_PT3 32L      // 2 * 16
#define WB_TOTAL (WB_HW+WB_W1+WB_W2+WB_W3+WB_HID+WB_PT0+WB_PT1+WB_PT2+WB_PT3) // 41856

__global__ __launch_bounds__(256) void prep_wswz(
    const float* __restrict__ hidden,
    const float* __restrict__ W0, const float* __restrict__ cw,
    const float* __restrict__ W1, const float* __restrict__ W2, const float* __restrict__ W3,
    const float* __restrict__ p0, const float* __restrict__ p1,
    const float* __restrict__ p2, const float* __restrict__ p3,
    ushort* __restrict__ hw, ushort* __restrict__ ow1,
    ushort* __restrict__ ow2, ushort* __restrict__ ow3,
    ushort* __restrict__ hid,
    ushort* __restrict__ pT0, ushort* __restrict__ pT1,
    ushort* __restrict__ pT2, ushort* __restrict__ pT3)
{
    int lane = threadIdx.x & 63;
    int r = lane & 15, quad = lane >> 4;
    long wb0 = (long)blockIdx.x * 4 + (threadIdx.x >> 6);
    long nw = (long)gridDim.x * 4;
    for (long wb = wb0; wb < WB_TOTAL; wb += nw) {
        long b = wb;
        float vals[8];
        #pragma unroll
        for (int j = 0; j < 8; ++j) vals[j] = 0.f;
        ushort* dst;
        if (b < WB_HW) {                         // head weights, K=512
            long tile = b >> 4, ks = b & 15;
            long v = tile * 16 + r, k = ks * 32 + quad * 8;
            if (v < 20000)      ld8(W0 + v * 512 + k, vals);
            else if (v < VH)    ld8(cw + (v - 20000) * 512 + k, vals);
            dst = hw + b * 512 + (long)lane * 8;
        } else if ((b -= WB_HW) < WB_W1) {       // W1, K=128
            long tile = b >> 2, ks = b & 3;
            long v = tile * 16 + r, k = ks * 32 + quad * 8;
            if (v < V1) ld8(W1 + v * 128 + k, vals);
            dst = ow1 + b * 512 + (long)lane * 8;
        } else if ((b -= WB_W1) < WB_W2) {       // W2, K=32 (1 block/tile)
            long v = b * 16 + r;
            if (v < V2) ld8(W2 + v * 32 + quad * 8, vals);
            dst = ow2 + b * 512 + (long)lane * 8;
        } else if ((b -= WB_W2) < WB_W3) {       // W3, K=32 padded from 8
            long v = b * 16 + r;
            if (v < V3 && quad == 0) ld8(W3 + v * 8, vals);
            dst = ow3 + b * 512 + (long)lane * 8;
        } else if ((b -= WB_W3) < WB_HID) {      // hidden, K=512
            long tile = b >> 4, ks = b & 15;
            long v = tile * 16 + r, k = ks * 32 + quad * 8;
            ld8(hidden + v * 512 + k, vals);
            dst = hid + b * 512 + (long)lane * 8;
        } else if ((b -= WB_HID) < WB_PT0) {     // projT0: "rows" = cols of p0 [512][512]
            long tile = b >> 4, ks = b & 15;
            long c = tile * 16 + r, k = ks * 32 + quad * 8;
            #pragma unroll
            for (int j = 0; j < 8; ++j) vals[j] = p0[(k + j) * 512 + c];
            dst = pT0 + b * 512 + (long)lane * 8;
        } else if ((b -= WB_PT0) < WB_PT1) {     // projT1 [512][128] -> cols 0..127
            long tile = b >> 4, ks = b & 15;
            long c = tile * 16 + r, k = ks * 32 + quad * 8;
            #pragma unroll
            for (int j = 0; j < 8; ++j) vals[j] = p1[(k + j) * 128 + c];
            dst = pT1 + b * 512 + (long)lane * 8;
        } else if ((b -= WB_PT1) < WB_PT2) {     // projT2 [512][32]
            long tile = b >> 4, ks = b & 15;
            long c = tile * 16 + r, k = ks * 32 + quad * 8;
            #pragma unroll
            for (int j = 0; j < 8; ++j) vals[j] = p2[(k + j) * 32 + c];
            dst = pT2 + b * 512 + (long)lane * 8;
        } else {                                 // projT3 [512][8] padded to 32 cols
            b -= WB_PT2;
            long tile = b >> 4, ks = b & 15;
            long c = tile * 16 + r, k = ks * 32 + quad * 8;
            if (c < 8) {
                #pragma unroll
                for (int j = 0; j < 8; ++j) vals[j] = p3[(k + j) * 8 + c];
            }
            dst = pT3 + b * 512 + (long)lane * 8;
        }
        u16x8 o;
        #pragma unroll
        for (int j = 0; j < 8; ++j) o[j] = f2bf(vals[j]);
        *(u16x8*)dst = o;
    }
}

// ---------------- prep: padded biases ----------------
#define E_HB  ((long)VH_PAD)
#define E_B1  ((long)V1_PAD)
#define E_B2  ((long)V2_PAD)
#define E_B3  ((long)V3_PAD)
#define E_BIAS (E_HB+E_B1+E_B2+E_B3)

__global__ __launch_bounds__(256) void prep_bias(
    const float* __restrict__ b0, const float* __restrict__ b1,
    const float* __restrict__ b2, const float* __restrict__ b3,
    const float* __restrict__ cb,
    float* __restrict__ hbp, float* __restrict__ ob1,
    float* __restrict__ ob2, float* __restrict__ ob3)
{
    long stride = (long)gridDim.x * blockDim.x;
    for (long i = (long)blockIdx.x * blockDim.x + threadIdx.x; i < E_BIAS; i += stride) {
        long j = i;
        if (j < E_HB) {
            hbp[j] = (j < 20000) ? b0[j] : (j < VH) ? cb[j - 20000] : PAD_BIAS;
        } else if ((j -= E_HB) < E_B1) {
            ob1[j] = (j < V1) ? b1[j] : PAD_BIAS;
        } else if ((j -= E_B1) < E_B2) {
            ob2[j] = (j < V2) ? b2[j] : PAD_BIAS;
        } else { j -= E_B2;
            ob3[j] = (j < V3) ? b3[j] : PAD_BIAS;
        }
    }
}

// ---------------- gemm_h: H_i = hidden @ proj_i (all operands swizzled) ----------------
__global__ __launch_bounds__(256) void gemm_h(
    const ushort* __restrict__ A, const ushort* __restrict__ Bt,
    ushort* __restrict__ Hout, int dpad)
{
    int wave = threadIdx.x >> 6, lane = threadIdx.x & 63;
    int quad = lane >> 4, colid = lane & 15;
    int m_tile = blockIdx.x * 4 + wave;
    int c_tile = blockIdx.y;
    const ushort* Ab = A + ((long)m_tile * 16) * 512 + lane * 8;   // hid K=512 -> 16 blocks/tile
    const ushort* Bb = Bt + ((long)c_tile * 16) * 512 + lane * 8;
    f32x4 acc = {0.f, 0.f, 0.f, 0.f};
    #pragma unroll
    for (int ks = 0; ks < 16; ++ks) {
        s16x8 a = *(const s16x8*)(Ab + ks * 512);
        s16x8 b = *(const s16x8*)(Bb + ks * 512);
        acc = mfma_bf16(a, b, acc);
    }
    // write H in swizzled layout (its K = dpad)
    int KBo = dpad >> 5;
    int col = c_tile * 16 + colid;
    int ks_o = col >> 5, q_o = (col >> 3) & 3, j_o = col & 7;
    #pragma unroll
    for (int r = 0; r < 4; ++r) {
        int rm = quad * 4 + r;
        Hout[((long)m_tile * KBo + ks_o) * 512 + (q_o * 16 + rm) * 8 + j_o] = f2bf(acc[r]);
    }
}

// ---------------- fused GEMM + exp-sum over vocab chunk (swizzled operands) ----------------
template<int K, int U>
__global__ __launch_bounds__(256, 4) void fused_lse_t(
    const ushort* __restrict__ A, const ushort* __restrict__ W,
    const float* __restrict__ bias, float* __restrict__ part_s,
    int tpc, int n_chunks)
{
    constexpr int KB = K / 32;
    int wave = threadIdx.x >> 6, lane = threadIdx.x & 63;
    int quad = lane >> 4, colid = lane & 15;
    int m_tile = blockIdx.x * 4 + wave;
    int t0 = blockIdx.y * tpc;
    const ushort* Ab = A + ((long)m_tile * KB) * 512 + lane * 8;
    float s_acc[4] = {0.f, 0.f, 0.f, 0.f};

    for (int vt = 0; vt < tpc; vt += U) {
        int tile0 = t0 + vt;
        const ushort* Wb = W + ((long)tile0 * KB) * 512 + lane * 8;
        f32x4 acc[U];
        #pragma unroll
        for (int u = 0; u < U; ++u) acc[u] = (f32x4){0.f, 0.f, 0.f, 0.f};
        #pragma unroll 4
        for (int ks = 0; ks < KB; ++ks) {
            s16x8 a = *(const s16x8*)(Ab + ks * 512);
            #pragma unroll
            for (int u = 0; u < U; ++u) {
                s16x8 b = *(const s16x8*)(Wb + ((long)u * KB + ks) * 512);
                acc[u] = mfma_bf16(a, b, acc[u]);
            }
        }
        #pragma unroll
        for (int u = 0; u < U; ++u) {
            float bval = bias[(tile0 + u) * 16 + colid];
            #pragma unroll
            for (int r = 0; r < 4; ++r)
                s_acc[r] += __expf(acc[u][r] + bval);
        }
    }
    #pragma unroll
    for (int r = 0; r < 4; ++r) {
        float v = s_acc[r];
        v += __shfl_xor(v, 1);
        v += __shfl_xor(v, 2);
        v += __shfl_xor(v, 4);
        v += __shfl_xor(v, 8);
        s_acc[r] = v;
    }
    if (colid == 0) {
        #pragma unroll
        for (int r = 0; r < 4; ++r) {
            int m = m_tile * 16 + quad * 4 + r;
            part_s[(long)m * n_chunks + blockIdx.y] = s_acc[r];
        }
    }
}

// ---------------- finalize ----------------
// dot of swizzled H row m with swizzled W row vrow over K; returns sum on all lanes
__device__ __forceinline__ float swz_dot(const ushort* __restrict__ H, int m,
                                         const ushort* __restrict__ Wm, long vrow,
                                         int K, int lane)
{
    float d = 0.f;
    if (lane * 8 < K) {
        int ks = lane >> 2, q = lane & 3;
        int KB = K >> 5;
        const ushort* hp = H + ((long)(m >> 4) * KB + ks) * 512 + (q * 16 + (m & 15)) * 8;
        const ushort* wp = Wm + ((vrow >> 4) * KB + ks) * 512 + (q * 16 + (int)(vrow & 15)) * 8;
        #pragma unroll
        for (int j = 0; j < 8; ++j) d += bf2f(hp[j]) * bf2f(wp[j]);
    }
    d += __shfl_xor(d, 1);  d += __shfl_xor(d, 2);  d += __shfl_xor(d, 4);
    d += __shfl_xor(d, 8);  d += __shfl_xor(d, 16); d += __shfl_xor(d, 32);
    return d;
}

__global__ __launch_bounds__(256) void finalize_kernel(
    const int* __restrict__ target,
    const ushort* __restrict__ H0, const ushort* __restrict__ hw,
    const float* __restrict__ hbp, const float* __restrict__ sH,
    const ushort* __restrict__ H1, const ushort* __restrict__ w1,
    const float* __restrict__ b1p, const float* __restrict__ s1,
    const ushort* __restrict__ H2, const ushort* __restrict__ w2,
    const float* __restrict__ b2p, const float* __restrict__ s2,
    const ushort* __restrict__ H3, const ushort* __restrict__ w3,
    const float* __restrict__ b3p, const float* __restrict__ s3,
    float* __restrict__ out)
{
    int wave = threadIdx.x >> 6, lane = threadIdx.x & 63;
    int m = blockIdx.x * 4 + wave;
    int t = target[m];
    int cid = (t >= 20000) + (t >= 40000) + (t >= 200000);

    float s = 0.f;
    for (int i = lane; i < NCH_H; i += 64) s += sH[(long)m * NCH_H + i];
    s += __shfl_xor(s, 1);  s += __shfl_xor(s, 2);  s += __shfl_xor(s, 4);
    s += __shfl_xor(s, 8);  s += __shfl_xor(s, 16); s += __shfl_xor(s, 32);
    float lse_h = __logf(s);

    int hc = (cid == 0) ? t : (20003 - cid);
    float d = swz_dot(H0, m, hw, hc, 512, lane);
    float nll = lse_h - (d + hbp[hc]);

    if (cid > 0) {
        const ushort *Hi, *Wi; const float *bi, *si; int K, nc, l;
        if (cid == 1)      { Hi = H1; Wi = w1; bi = b1p; si = s1; K = 128; nc = NCH_1; l = 20000; }
        else if (cid == 2) { Hi = H2; Wi = w2; bi = b2p; si = s2; K = 32;  nc = NCH_2; l = 40000; }
        else               { Hi = H3; Wi = w3; bi = b3p; si = s3; K = 32;  nc = NCH_3; l = 200000; }
        int rel = t - l;
        float ts = 0.f;
        for (int i = lane; i < nc; i += 64) ts += si[(long)m * nc + i];
        ts += __shfl_xor(ts, 1);  ts += __shfl_xor(ts, 2);  ts += __shfl_xor(ts, 4);
        ts += __shfl_xor(ts, 8);  ts += __shfl_xor(ts, 16); ts += __shfl_xor(ts, 32);
        float lse_t = __logf(ts);
        float dt = swz_dot(Hi, m, Wi, rel, K, lane);
        nll += lse_t - (dt + bi[rel]);
    }
    if (lane == 0) out[m] = nll;
}

// ---------------- host ----------------
extern "C" void kernel_launch(void* const* d_in, const int* in_sizes, int n_in,
                              void* d_out, int out_size, void* d_ws, size_t ws_size,
                              hipStream_t stream) {
    const float* hidden = (const float*)d_in[0];
    const int*   target = (const int*)d_in[1];
    const float* W0 = (const float*)d_in[2];
    const float* b0 = (const float*)d_in[3];
    const float* p0 = (const float*)d_in[4];
    const float* W1 = (const float*)d_in[5];
    const float* b1 = (const float*)d_in[6];
    const float* p1 = (const float*)d_in[7];
    const float* W2 = (const float*)d_in[8];
    const float* b2 = (const float*)d_in[9];
    const float* p2 = (const float*)d_in[10];
    const float* W3 = (const float*)d_in[11];
    const float* b3 = (const float*)d_in[12];
    const float* p3 = (const float*)d_in[13];
    const float* cw = (const float*)d_in[14];
    const float* cb = (const float*)d_in[15];

    char* ws = (char*)d_ws;
    ushort* hw  = (ushort*)(ws + OFF_HW);
    ushort* ow1 = (ushort*)(ws + OFF_W1);
    ushort* ow2 = (ushort*)(ws + OFF_W2);
    ushort* ow3 = (ushort*)(ws + OFF_W3);
    ushort* hid = (ushort*)(ws + OFF_HID);
    ushort* pT0 = (ushort*)(ws + OFF_PT0);
    ushort* pT1 = (ushort*)(ws + OFF_PT1);
    ushort* pT2 = (ushort*)(ws + OFF_PT2);
    ushort* pT3 = (ushort*)(ws + OFF_PT3);
    ushort* H0  = (ushort*)(ws + OFF_H0);
    ushort* H1  = (ushort*)(ws + OFF_H1);
    ushort* H2  = (ushort*)(ws + OFF_H2);
    ushort* H3  = (ushort*)(ws + OFF_H3);
    float* hbp = (float*)(ws + OFF_HB);
    float* b1p = (float*)(ws + OFF_B1);
    float* b2p = (float*)(ws + OFF_B2);
    float* b3p = (float*)(ws + OFF_B3);
    float* sH  = (float*)(ws + OFF_SH);
    float* s1  = (float*)(ws + OFF_S1);
    float* s2  = (float*)(ws + OFF_S2);
    float* s3  = (float*)(ws + OFF_S3);

    prep_wswz<<<10464, 256, 0, stream>>>(hidden, W0, cw, W1, W2, W3,
                                         p0, p1, p2, p3,
                                         hw, ow1, ow2, ow3, hid, pT0, pT1, pT2, pT3);
    prep_bias<<<1072, 256, 0, stream>>>(b0, b1, b2, b3, cb, hbp, b1p, b2p, b3p);

    gemm_h<<<dim3(NTOK / 64, 512 / 16), 256, 0, stream>>>(hid, pT0, H0, 512);
    gemm_h<<<dim3(NTOK / 64, 128 / 16), 256, 0, stream>>>(hid, pT1, H1, 128);
    gemm_h<<<dim3(NTOK / 64, 32 / 16),  256, 0, stream>>>(hid, pT2, H2, 32);
    gemm_h<<<dim3(NTOK / 64, 32 / 16),  256, 0, stream>>>(hid, pT3, H3, 32);

    fused_lse_t<KH, 8><<<dim3(NTOK / 64, NCH_H), 256, 0, stream>>>(H0, hw,  hbp, sH, TPC_H, NCH_H);
    fused_lse_t<K1, 8><<<dim3(NTOK / 64, NCH_1), 256, 0, stream>>>(H1, ow1, b1p, s1, TPC_1, NCH_1);
    fused_lse_t<K2, 8><<<dim3(NTOK / 64, NCH_2), 256, 0, stream>>>(H2, ow2, b2p, s2, TPC_2, NCH_2);
    fused_lse_t<K3, 8><<<dim3(NTOK / 64, NCH_3), 256, 0, stream>>>(H3, ow3, b3p, s3, TPC_3, NCH_3);

    finalize_kernel<<<NTOK / 4, 256, 0, stream>>>(target,
        H0, hw, hbp, sH, H1, ow1, b1p, s1, H2, ow2, b2p, s2, H3, ow3, b3p, s3,
        (float*)d_out);
}